// Round 3
// baseline (264.001 us; speedup 1.0000x reference)
//
#include <hip/hip_runtime.h>
#include <math.h>

// Problem constants
#define B_TOT 2048
#define S_LEN 256
#define DIN   3
#define H     128
#define DOUT  6
#define DT_C  0.1f

#define NROWS 4    // batch rows per block -> grid = 512 = 2 blocks/CU (2 barrier groups)
#define HPAD  136  // bf16 row stride in LDS (128 + 8 pad)

// XOR swizzle: physical column for (row c, logical col j). XORs bits >=4 only,
// so 4-aligned 4-runs (writes) and 8-aligned 8-runs (reads) stay contiguous.
#define SW(c, j) ((j) ^ (((c) & 7) << 4))

typedef __attribute__((ext_vector_type(8))) short short8;
typedef __attribute__((ext_vector_type(4))) float f32x4;
typedef __attribute__((ext_vector_type(2))) unsigned int u32x2;

__device__ __forceinline__ unsigned short f2bf(float f) {
  unsigned int u = __float_as_uint(f);
  u += 0x7FFFu + ((u >> 16) & 1u);          // round-to-nearest-even
  return (unsigned short)(u >> 16);
}
__device__ __forceinline__ float bf2f(unsigned short h) {
  return __uint_as_float(((unsigned int)h) << 16);
}

// One block = NROWS batch rows, 512 threads (8 waves). Wave w owns j-tile [w*16, w*16+16).
// Step GEMM via mfma_f32_16x16x32_bf16, A = W_hh (m=j), B = h^T (n=b):
//   lane holds (b = lane&15, j = w*16 + quad*4 + r)
// W split hi/lo in registers; h bf16 in swizzled LDS; ping-pong, ONE barrier/step.
__launch_bounds__(512, 4)
__global__ void ltc_kernel(const float* __restrict__ x,
                           const float* __restrict__ W_xh,
                           const float* __restrict__ W_hh,
                           const float* __restrict__ b_hh,
                           const float* __restrict__ log_tau,
                           const float* __restrict__ fc_W,
                           const float* __restrict__ fc_b,
                           float* __restrict__ out) {
  __shared__ alignas(16) unsigned short sh_h[2][16][HPAD];  // ping-pong h bf16; rows NROWS..15 stay 0
  __shared__ alignas(16) float sh_hf[NROWS][132];           // final h fp32 for head

  const int tid  = threadIdx.x;
  const int w    = tid >> 6;        // wave 0..7 -> j-tile
  const int lane = tid & 63;
  const int quad = lane >> 4;       // 0..3
  const int l16  = lane & 15;       // b-column in B/D fragments
  const int rb0  = blockIdx.x * NROWS;

  // ---- zero both h buffers (rows NROWS..15 remain zero -> zero-padded B cols) ----
  {
    uint4* p = (uint4*)&sh_h[0][0][0];
    const int n16 = (2 * 16 * HPAD) / 8;  // shorts -> uint4 count
    for (int i = tid; i < n16; i += 512) p[i] = make_uint4(0, 0, 0, 0);
  }

  // ---- W_hh A-fragments (hi/lo split), register-resident all 256 steps ----
  // A[m=l16][k = kc*32 + quad*8 + i],  j = w*16 + m
  short8 wa_hi[4], wa_lo[4];
  {
    const int j = w * 16 + l16;
#pragma unroll
    for (int kc = 0; kc < 4; ++kc) {
      const float* src = W_hh + j * H + kc * 32 + quad * 8;
#pragma unroll
      for (int i = 0; i < 8; ++i) {
        float wv = src[i];
        unsigned short hi = f2bf(wv);
        unsigned short lo = f2bf(wv - bf2f(hi));
        wa_hi[kc][i] = (short)hi;
        wa_lo[kc][i] = (short)lo;
      }
    }
  }

  // ---- per-lane epilogue constants for j = w*16 + quad*4 + r ----
  float wx[4][3], bh4[4], cc4[4];
#pragma unroll
  for (int r = 0; r < 4; ++r) {
    const int j = w * 16 + quad * 4 + r;
    wx[r][0] = W_xh[j * 3 + 0];
    wx[r][1] = W_xh[j * 3 + 1];
    wx[r][2] = W_xh[j * 3 + 2];
    bh4[r]   = b_hh[j];
    float lt = log_tau[j];
    float tau = logf(1.f + expf(lt)) + 0.001f;   // softplus + eps, exact fp32, once
    cc4[r]   = DT_C / tau;
  }

  // ---- x stream for this lane's batch row (prefetch 1 step ahead) ----
  const int brow = l16 & (NROWS - 1);
  const bool valid = (l16 < NROWS);
  const float* xrow = x + (size_t)(rb0 + brow) * (S_LEN * DIN);
  float xc0 = xrow[0], xc1 = xrow[1], xc2 = xrow[2];

  float hreg[4] = {0.f, 0.f, 0.f, 0.f};  // fp32 h state, lane-resident

  __syncthreads();

  for (int s = 0; s < S_LEN; ++s) {
    // prefetch next step's x (independent of this step's compute)
    const int sn = (s < S_LEN - 1) ? s + 1 : s;
    float xn0 = xrow[sn * 3 + 0];
    float xn1 = xrow[sn * 3 + 1];
    float xn2 = xrow[sn * 3 + 2];

    // B-fragments of h^T from current buffer: B[k = kc*32+quad*8+i][n = l16]
    const unsigned short (*hb)[HPAD] = sh_h[s & 1];
    short8 bf[4];
#pragma unroll
    for (int kc = 0; kc < 4; ++kc)
      bf[kc] = *(const short8*)&hb[l16][SW(l16, kc * 32 + quad * 8)];

    // two independent 4-deep MFMA chains (Whi*h and Wlo*h)
    f32x4 ah = {0.f, 0.f, 0.f, 0.f};
    f32x4 al = {0.f, 0.f, 0.f, 0.f};
#pragma unroll
    for (int kc = 0; kc < 4; ++kc) {
      ah = __builtin_amdgcn_mfma_f32_16x16x32_bf16(wa_hi[kc], bf[kc], ah, 0, 0, 0);
      al = __builtin_amdgcn_mfma_f32_16x16x32_bf16(wa_lo[kc], bf[kc], al, 0, 0, 0);
    }

    // epilogue: preact = Wh + b + x@W_xh^T ; f=tanh via exp+rcp ; h += (DT/tau)*(f-h)
#pragma unroll
    for (int r = 0; r < 4; ++r) {
      float pre = ah[r] + al[r] + bh4[r]
                + xc0 * wx[r][0] + xc1 * wx[r][1] + xc2 * wx[r][2];
      float t = __builtin_amdgcn_rcpf(__expf(2.f * pre) + 1.f);
      float f = 1.f - 2.f * t;             // tanh, correct at +/-inf
      hreg[r] += cc4[r] * (f - hreg[r]);
    }

    // write next-step h (bf16) into the OTHER buffer; one barrier separates steps
    if (valid) {
      unsigned short h0 = f2bf(hreg[0]);
      unsigned short h1 = f2bf(hreg[1]);
      unsigned short h2 = f2bf(hreg[2]);
      unsigned short h3 = f2bf(hreg[3]);
      u32x2 v;
      v.x = (unsigned)h0 | ((unsigned)h1 << 16);
      v.y = (unsigned)h2 | ((unsigned)h3 << 16);
      *(u32x2*)&sh_h[(s + 1) & 1][brow][SW(brow, w * 16 + quad * 4)] = v;
    }
    __syncthreads();

    xc0 = xn0; xc1 = xn1; xc2 = xn2;
  }

  // ---- final head: params = softplus(h @ fc_W^T + fc_b), [NROWS x 6] per block ----
  if (valid) {
    f32x4 v = {hreg[0], hreg[1], hreg[2], hreg[3]};
    *(f32x4*)&sh_hf[brow][w * 16 + quad * 4] = v;
  }
  __syncthreads();

  if (tid < NROWS * DOUT) {
    const int b = tid / DOUT;
    const int o = tid - b * DOUT;
    const float* fw = fc_W + o * H;
    float acc = fc_b[o];
#pragma unroll 4
    for (int k = 0; k < H; ++k) acc += sh_hf[b][k] * fw[k];
    float sp = (acc > 15.f) ? acc : logf(1.f + expf(acc));
    out[(rb0 + b) * DOUT + o] = sp;
  }
}

extern "C" void kernel_launch(void* const* d_in, const int* in_sizes, int n_in,
                              void* d_out, int out_size, void* d_ws, size_t ws_size,
                              hipStream_t stream) {
  const float* x       = (const float*)d_in[0];
  const float* W_xh    = (const float*)d_in[1];
  const float* W_hh    = (const float*)d_in[2];
  const float* b_hh    = (const float*)d_in[3];
  const float* log_tau = (const float*)d_in[4];
  const float* fc_W    = (const float*)d_in[5];
  const float* fc_b    = (const float*)d_in[6];
  float* out           = (float*)d_out;

  ltc_kernel<<<dim3(B_TOT / NROWS), dim3(512), 0, stream>>>(
      x, W_xh, W_hh, b_hh, log_tau, fc_W, fc_b, out);
}

// Round 4
// 201.297 us; speedup vs baseline: 1.3115x; 1.3115x over previous
//
#include <hip/hip_runtime.h>
#include <math.h>

// Problem constants
#define B_TOT 2048
#define S_LEN 256
#define DIN   3
#define H     128
#define DOUT  6
#define DT_C  0.1f

#define NROWS 8    // batch rows per block -> grid = 256 = 1 block/CU
#define HPAD  136  // bf16 row stride in LDS (128 + 8 pad) -- R2 layout (measured best)

typedef __attribute__((ext_vector_type(8))) short short8;
typedef __attribute__((ext_vector_type(4))) float f32x4;
typedef __attribute__((ext_vector_type(2))) unsigned int u32x2;

__device__ __forceinline__ unsigned short f2bf(float f) {
  unsigned int u = __float_as_uint(f);
  u += 0x7FFFu + ((u >> 16) & 1u);          // round-to-nearest-even
  return (unsigned short)(u >> 16);
}
__device__ __forceinline__ float bf2f(unsigned short h) {
  return __uint_as_float(((unsigned int)h) << 16);
}

// One block = 8 batch rows, 256 threads (4 waves). Wave w owns j-tile [w*32, w*32+32)
// as TWO 16-wide m-tiles sharing the same B-fragments (B depends only on (k,n)).
// Step GEMM via mfma_f32_16x16x32_bf16, A = W_hh (m=j), B = h^T (n=b):
//   lane holds (b = lane&15, j = w*32 + t*16 + quad*4 + r)
// W split hi/lo in registers (fp32-grade); h bf16 in LDS; ping-pong, ONE barrier/step,
// step loop unrolled x2 so buffer addresses are compile-time static.
__launch_bounds__(256, 1)
__global__ void ltc_kernel(const float* __restrict__ x,
                           const float* __restrict__ W_xh,
                           const float* __restrict__ W_hh,
                           const float* __restrict__ b_hh,
                           const float* __restrict__ log_tau,
                           const float* __restrict__ fc_W,
                           const float* __restrict__ fc_b,
                           float* __restrict__ out) {
  __shared__ alignas(16) unsigned short sh_h[2][16][HPAD];  // ping-pong h bf16; rows 8..15 stay 0
  __shared__ alignas(16) float sh_hf[NROWS][132];           // final h fp32 for head

  const int tid  = threadIdx.x;
  const int w    = tid >> 6;        // wave 0..3 -> j-tile [w*32, w*32+32)
  const int lane = tid & 63;
  const int quad = lane >> 4;       // 0..3
  const int l16  = lane & 15;       // b-column in B/D fragments
  const int rb0  = blockIdx.x * NROWS;

  // ---- zero both h buffers (rows 8..15 remain zero -> zero-padded B cols) ----
  {
    uint4* p = (uint4*)&sh_h[0][0][0];
    const int n16 = (2 * 16 * HPAD) / 8;  // shorts -> uint4 count
    for (int i = tid; i < n16; i += 256) p[i] = make_uint4(0, 0, 0, 0);
  }

  // ---- W_hh A-fragments (hi/lo split), register-resident all 256 steps ----
  // A[m=l16][k = kc*32 + quad*8 + i],  j = w*32 + t*16 + m
  short8 wa_hi[2][4], wa_lo[2][4];
#pragma unroll
  for (int t = 0; t < 2; ++t) {
    const int j = w * 32 + t * 16 + l16;
#pragma unroll
    for (int kc = 0; kc < 4; ++kc) {
      const float* src = W_hh + j * H + kc * 32 + quad * 8;
#pragma unroll
      for (int i = 0; i < 8; ++i) {
        float wv = src[i];
        unsigned short hi = f2bf(wv);
        unsigned short lo = f2bf(wv - bf2f(hi));
        wa_hi[t][kc][i] = (short)hi;
        wa_lo[t][kc][i] = (short)lo;
      }
    }
  }

  // ---- per-lane epilogue constants for j = w*32 + t*16 + quad*4 + r ----
  float wx[2][4][3], bh4[2][4], cc4[2][4];
#pragma unroll
  for (int t = 0; t < 2; ++t)
#pragma unroll
    for (int r = 0; r < 4; ++r) {
      const int j = w * 32 + t * 16 + quad * 4 + r;
      wx[t][r][0] = W_xh[j * 3 + 0];
      wx[t][r][1] = W_xh[j * 3 + 1];
      wx[t][r][2] = W_xh[j * 3 + 2];
      bh4[t][r]   = b_hh[j];
      float lt  = log_tau[j];
      float tau = logf(1.f + expf(lt)) + 0.001f;   // softplus + eps, exact fp32, once
      cc4[t][r] = DT_C / tau;
    }

  // ---- x stream for this lane's batch row (prefetch 1 step ahead) ----
  const int brow = l16 & (NROWS - 1);
  const bool valid = (l16 < NROWS);
  const float* xrow = x + (size_t)(rb0 + brow) * (S_LEN * DIN);
  float xc0 = xrow[0], xc1 = xrow[1], xc2 = xrow[2];

  float hreg[2][4] = {};  // fp32 h state, lane-resident

  // static LDS offsets (shorts)
  const int rd_off = l16 * HPAD + quad * 8;              // + kc*32
  const int wr_off = brow * HPAD + w * 32 + quad * 4;    // + t*16
  const unsigned short* __restrict__ buf0 = &sh_h[0][0][0];
  unsigned short* __restrict__ buf1 = &sh_h[1][0][0];

  __syncthreads();

  auto do_step = [&](const unsigned short* __restrict__ cur,
                     unsigned short* __restrict__ nxt, int sn) {
    // prefetch next step's x (independent of this step's compute)
    float xn0 = xrow[sn * 3 + 0];
    float xn1 = xrow[sn * 3 + 1];
    float xn2 = xrow[sn * 3 + 2];

    // B-fragments of h^T: B[k = kc*32+quad*8+i][n = l16] -- shared by both m-tiles
    short8 bf[4];
#pragma unroll
    for (int kc = 0; kc < 4; ++kc)
      bf[kc] = *(const short8*)(cur + rd_off + kc * 32);

    // 4 independent 4-deep MFMA chains (2 m-tiles x hi/lo)
    f32x4 acch[2] = {{0.f,0.f,0.f,0.f},{0.f,0.f,0.f,0.f}};
    f32x4 accl[2] = {{0.f,0.f,0.f,0.f},{0.f,0.f,0.f,0.f}};
#pragma unroll
    for (int kc = 0; kc < 4; ++kc) {
#pragma unroll
      for (int t = 0; t < 2; ++t) {
        acch[t] = __builtin_amdgcn_mfma_f32_16x16x32_bf16(wa_hi[t][kc], bf[kc], acch[t], 0, 0, 0);
        accl[t] = __builtin_amdgcn_mfma_f32_16x16x32_bf16(wa_lo[t][kc], bf[kc], accl[t], 0, 0, 0);
      }
    }

    // epilogue: preact = Wh + b + x@W_xh^T ; tanh via exp+rcp ; h += (DT/tau)*(f-h)
#pragma unroll
    for (int t = 0; t < 2; ++t)
#pragma unroll
      for (int r = 0; r < 4; ++r) {
        float pre = acch[t][r] + accl[t][r] + bh4[t][r]
                  + xc0 * wx[t][r][0] + xc1 * wx[t][r][1] + xc2 * wx[t][r][2];
        float rc = __builtin_amdgcn_rcpf(__expf(2.f * pre) + 1.f);
        float f  = 1.f - 2.f * rc;           // tanh, correct at +/-inf
        hreg[t][r] += cc4[t][r] * (f - hreg[t][r]);
      }

    // write next-step h (bf16) into the other buffer; one barrier separates steps
    if (valid) {
#pragma unroll
      for (int t = 0; t < 2; ++t) {
        unsigned short h0 = f2bf(hreg[t][0]);
        unsigned short h1 = f2bf(hreg[t][1]);
        unsigned short h2 = f2bf(hreg[t][2]);
        unsigned short h3 = f2bf(hreg[t][3]);
        u32x2 v;
        v.x = (unsigned)h0 | ((unsigned)h1 << 16);
        v.y = (unsigned)h2 | ((unsigned)h3 << 16);
        *(u32x2*)(nxt + wr_off + t * 16) = v;
      }
    }
    __syncthreads();

    xc0 = xn0; xc1 = xn1; xc2 = xn2;
  };

  for (int s = 0; s < S_LEN; s += 2) {
    do_step(buf0, buf1, s + 1);
    do_step(buf1, (unsigned short*)buf0, (s + 2 < S_LEN) ? s + 2 : S_LEN - 1);
  }

  // ---- final head: params = softplus(h @ fc_W^T + fc_b), [8 x 6] per block ----
  if (valid) {
#pragma unroll
    for (int t = 0; t < 2; ++t) {
      f32x4 v = {hreg[t][0], hreg[t][1], hreg[t][2], hreg[t][3]};
      *(f32x4*)&sh_hf[brow][w * 32 + t * 16 + quad * 4] = v;
    }
  }
  __syncthreads();

  if (tid < NROWS * DOUT) {
    const int b = tid / DOUT;
    const int o = tid - b * DOUT;
    const float* fw = fc_W + o * H;
    float acc = fc_b[o];
#pragma unroll 4
    for (int k = 0; k < H; ++k) acc += sh_hf[b][k] * fw[k];
    float sp = (acc > 15.f) ? acc : logf(1.f + expf(acc));
    out[(rb0 + b) * DOUT + o] = sp;
  }
}

extern "C" void kernel_launch(void* const* d_in, const int* in_sizes, int n_in,
                              void* d_out, int out_size, void* d_ws, size_t ws_size,
                              hipStream_t stream) {
  const float* x       = (const float*)d_in[0];
  const float* W_xh    = (const float*)d_in[1];
  const float* W_hh    = (const float*)d_in[2];
  const float* b_hh    = (const float*)d_in[3];
  const float* log_tau = (const float*)d_in[4];
  const float* fc_W    = (const float*)d_in[5];
  const float* fc_b    = (const float*)d_in[6];
  float* out           = (float*)d_out;

  ltc_kernel<<<dim3(B_TOT / NROWS), dim3(256), 0, stream>>>(
      x, W_xh, W_hh, b_hh, log_tau, fc_W, fc_b, out);
}

// Round 5
// 200.256 us; speedup vs baseline: 1.3183x; 1.0052x over previous
//
#include <hip/hip_runtime.h>
#include <math.h>

// Problem constants
#define B_TOT 2048
#define S_LEN 256
#define DIN   3
#define H     128
#define DOUT  6
#define DT_C  0.1f

#define NROWS 8    // batch rows per block -> grid = 256 = 1 block/CU
#define HPAD  136  // bf16 row stride in sh_h (128 + 8 pad), 272B = 16B aligned
#define PPAD  136  // f32 row stride in sh_p (128 + 8 pad), 544B = 16B aligned

typedef __attribute__((ext_vector_type(8))) short short8;
typedef __attribute__((ext_vector_type(4))) float f32x4;
typedef __attribute__((ext_vector_type(2))) unsigned int u32x2;

__device__ __forceinline__ unsigned short f2bf(float f) {
  unsigned int u = __float_as_uint(f);
  u += 0x7FFFu + ((u >> 16) & 1u);          // round-to-nearest-even
  return (unsigned short)(u >> 16);
}
__device__ __forceinline__ float bf2f(unsigned short h) {
  return __uint_as_float(((unsigned int)h) << 16);
}

// One block = 8 batch rows, 256 threads (4 waves). Wave w owns j-tile [w*32, w*32+32)
// as two 16-wide m-tiles sharing B-fragments.
// Phase 1 (MFMA): preact[j][b] = W_hh(hi+lo) . h  -> valid (b<8) lanes stage f32 to sh_p.
// Phase 2 (epilogue): thread owns 4 FIXED valid elems (b=tid>>5, j=(tid&31)*4 + 0..3):
//   h state register-resident across all 256 steps; tanh+integrate; bf16 h -> ping-pong sh_h.
// Two barriers/step; step loop unrolled x2 for static ping-pong addresses.
__launch_bounds__(256, 1)
__global__ void ltc_kernel(const float* __restrict__ x,
                           const float* __restrict__ W_xh,
                           const float* __restrict__ W_hh,
                           const float* __restrict__ b_hh,
                           const float* __restrict__ log_tau,
                           const float* __restrict__ fc_W,
                           const float* __restrict__ fc_b,
                           float* __restrict__ out) {
  __shared__ alignas(16) unsigned short sh_h[2][16][HPAD];  // ping-pong h bf16; rows 8..15 stay 0
  __shared__ alignas(16) float sh_p[NROWS][PPAD];           // preact staging / final h fp32

  const int tid  = threadIdx.x;
  const int w    = tid >> 6;        // wave 0..3 -> j-tile [w*32, w*32+32)
  const int lane = tid & 63;
  const int quad = lane >> 4;       // 0..3
  const int l16  = lane & 15;       // b-column in B/D fragments
  const int rb0  = blockIdx.x * NROWS;

  // ---- zero both h buffers (rows 8..15 remain zero -> zero-padded B cols) ----
  {
    uint4* p = (uint4*)&sh_h[0][0][0];
    const int n16 = (2 * 16 * HPAD) / 8;  // shorts -> uint4 count
    for (int i = tid; i < n16; i += 256) p[i] = make_uint4(0, 0, 0, 0);
  }

  // ---- W_hh A-fragments (hi/lo split), register-resident all 256 steps ----
  // A[m=l16][k = kc*32 + quad*8 + i],  j = w*32 + t*16 + m
  short8 wa_hi[2][4], wa_lo[2][4];
#pragma unroll
  for (int t = 0; t < 2; ++t) {
    const int j = w * 32 + t * 16 + l16;
#pragma unroll
    for (int kc = 0; kc < 4; ++kc) {
      const float* src = W_hh + j * H + kc * 32 + quad * 8;
#pragma unroll
      for (int i = 0; i < 8; ++i) {
        float wv = src[i];
        unsigned short hi = f2bf(wv);
        unsigned short lo = f2bf(wv - bf2f(hi));
        wa_hi[t][kc][i] = (short)hi;
        wa_lo[t][kc][i] = (short)lo;
      }
    }
  }

  // ---- epilogue-thread mapping: 4 valid elems, fixed for all steps ----
  const int eb = tid >> 5;          // batch row 0..7
  const int ej = (tid & 31) * 4;    // j base 0..124
  float ewx[4][3], ebh[4], ecc[4];
#pragma unroll
  for (int r = 0; r < 4; ++r) {
    const int j = ej + r;
    ewx[r][0] = W_xh[j * 3 + 0];
    ewx[r][1] = W_xh[j * 3 + 1];
    ewx[r][2] = W_xh[j * 3 + 2];
    ebh[r]    = b_hh[j];
    float lt  = log_tau[j];
    float tau = logf(1.f + expf(lt)) + 0.001f;   // softplus + eps, exact fp32, once
    ecc[r]    = DT_C / tau;
  }
  const float* xrow = x + (size_t)(rb0 + eb) * (S_LEN * DIN);

  float hreg[4] = {0.f, 0.f, 0.f, 0.f};  // fp32 h for (eb, ej..ej+3), register-resident

  // static LDS offsets
  const int rd_off  = l16 * HPAD + quad * 8;             // B-frag read base (+ kc*32)
  const int wrp_off = l16 * PPAD + w * 32 + quad * 4;    // preact store (valid lanes, + t*16)
  const int ep_off  = eb * PPAD + ej;                    // epilogue preact read
  const int eh_off  = eb * HPAD + ej;                    // epilogue h write (shorts)
  const bool pvalid = (l16 < NROWS);
  float* const shp = &sh_p[0][0];
  const unsigned short* __restrict__ buf0 = &sh_h[0][0][0];
  unsigned short* __restrict__ buf1 = &sh_h[1][0][0];

  __syncthreads();

  auto do_step = [&](const unsigned short* __restrict__ cur,
                     unsigned short* __restrict__ nxt, int s) {
    // issue x load for THIS step's epilogue early (hidden behind MFMA + barrier)
    float xc0 = xrow[s * 3 + 0];
    float xc1 = xrow[s * 3 + 1];
    float xc2 = xrow[s * 3 + 2];

    // B-fragments of h^T: B[k = kc*32+quad*8+i][n = l16] -- shared by both m-tiles
    short8 bf[4];
#pragma unroll
    for (int kc = 0; kc < 4; ++kc)
      bf[kc] = *(const short8*)(cur + rd_off + kc * 32);

    // 4 independent 4-deep MFMA chains (2 m-tiles x hi/lo)
    f32x4 acch[2] = {{0.f,0.f,0.f,0.f},{0.f,0.f,0.f,0.f}};
    f32x4 accl[2] = {{0.f,0.f,0.f,0.f},{0.f,0.f,0.f,0.f}};
#pragma unroll
    for (int kc = 0; kc < 4; ++kc) {
#pragma unroll
      for (int t = 0; t < 2; ++t) {
        acch[t] = __builtin_amdgcn_mfma_f32_16x16x32_bf16(wa_hi[t][kc], bf[kc], acch[t], 0, 0, 0);
        accl[t] = __builtin_amdgcn_mfma_f32_16x16x32_bf16(wa_lo[t][kc], bf[kc], accl[t], 0, 0, 0);
      }
    }

    // stage valid preact (b < 8) to LDS
    if (pvalid) {
#pragma unroll
      for (int t = 0; t < 2; ++t) {
        f32x4 v;
#pragma unroll
        for (int r = 0; r < 4; ++r) v[r] = acch[t][r] + accl[t][r];
        *(f32x4*)(shp + wrp_off + t * 16) = v;
      }
    }
    __syncthreads();

    // dense epilogue: 4 valid elems per thread
    f32x4 p = *(const f32x4*)(shp + ep_off);
    unsigned int pk[2];
#pragma unroll
    for (int r = 0; r < 4; ++r) {
      float pre = p[r] + ebh[r] + xc0 * ewx[r][0] + xc1 * ewx[r][1] + xc2 * ewx[r][2];
      float rc  = __builtin_amdgcn_rcpf(__expf(2.f * pre) + 1.f);
      float f   = 1.f - 2.f * rc;            // tanh, correct at +/-inf
      hreg[r] += ecc[r] * (f - hreg[r]);
    }
    pk[0] = (unsigned)f2bf(hreg[0]) | ((unsigned)f2bf(hreg[1]) << 16);
    pk[1] = (unsigned)f2bf(hreg[2]) | ((unsigned)f2bf(hreg[3]) << 16);
    u32x2 hv; hv.x = pk[0]; hv.y = pk[1];
    *(u32x2*)(nxt + eh_off) = hv;            // 8B store, row b, cols ej..ej+3
    __syncthreads();
  };

  for (int s = 0; s < S_LEN; s += 2) {
    do_step(buf0, buf1, s);
    do_step(buf1, (unsigned short*)buf0, s + 1);
  }

  // ---- final head: params = softplus(h @ fc_W^T + fc_b), [8 x 6] per block ----
  {
    f32x4 v = {hreg[0], hreg[1], hreg[2], hreg[3]};
    *(f32x4*)(shp + ep_off) = v;             // full-precision h into sh_p
  }
  __syncthreads();

  if (tid < NROWS * DOUT) {
    const int b = tid / DOUT;
    const int o = tid - b * DOUT;
    const float* fw = fc_W + o * H;
    float acc = fc_b[o];
#pragma unroll 4
    for (int k = 0; k < H; ++k) acc += sh_p[b][k] * fw[k];
    float sp = (acc > 15.f) ? acc : logf(1.f + expf(acc));
    out[(rb0 + b) * DOUT + o] = sp;
  }
}

extern "C" void kernel_launch(void* const* d_in, const int* in_sizes, int n_in,
                              void* d_out, int out_size, void* d_ws, size_t ws_size,
                              hipStream_t stream) {
  const float* x       = (const float*)d_in[0];
  const float* W_xh    = (const float*)d_in[1];
  const float* W_hh    = (const float*)d_in[2];
  const float* b_hh    = (const float*)d_in[3];
  const float* log_tau = (const float*)d_in[4];
  const float* fc_W    = (const float*)d_in[5];
  const float* fc_b    = (const float*)d_in[6];
  float* out           = (float*)d_out;

  ltc_kernel<<<dim3(B_TOT / NROWS), dim3(256), 0, stream>>>(
      x, W_xh, W_hh, b_hh, log_tau, fc_W, fc_b, out);
}